// Round 6
// baseline (2769.566 us; speedup 1.0000x reference)
//
#include <hip/hip_runtime.h>
#include <hip/hip_fp16.h>

#define TSEQ   2048
#define NB     64
#define NE     256
#define NH     256
#define NG     768
#define TCH    64
#define NCHUNK (TSEQ / TCH)

// LDS pool layout (rec branch): n-gate weights [131072 B] + h double-buffer
#define WN_BYTES   131072
#define H_OFF      131072
#define H_BUFSTR   576          // per-buffer stride (4 quarters x 144)
#define H_QSTR     144          // quarter stride: 128 data + 16 pad (bank-spread)
#define POOL_BYTES 132352

using half2_t = __attribute__((ext_vector_type(2))) _Float16;
typedef unsigned int u32x4 __attribute__((ext_vector_type(4)));
union U4 { u32x4 q; half2_t h[4]; };

__device__ __forceinline__ float dot2f(half2_t a, half2_t b, float c) {
#if __has_builtin(__builtin_amdgcn_fdot2)
  return __builtin_amdgcn_fdot2(a, b, c, false);
#else
  return c + (float)a[0] * (float)b[0] + (float)a[1] * (float)b[1];
#endif
}

__device__ __forceinline__ float fast_exp2(float x) {
#if __has_builtin(__builtin_amdgcn_exp2f)
  return __builtin_amdgcn_exp2f(x);
#else
  return exp2f(x);
#endif
}
__device__ __forceinline__ float fast_rcp(float x) {
#if __has_builtin(__builtin_amdgcn_rcpf)
  return __builtin_amdgcn_rcpf(x);
#else
  return 1.f / x;
#endif
}
__device__ __forceinline__ float sigm(float x) {
  return fast_rcp(1.f + fast_exp2(x * -1.44269504f));
}
__device__ __forceinline__ float tanh_fast(float x) {
  x = fminf(x, 15.f);
  float e = fast_exp2(x * 2.88539008f);
  return (e - 1.f) * fast_rcp(e + 1.f);
}

// ---------------------------------------------------------------------------
// Pack w_hh r,z rows (fp32 [768][256], rows 0..511) into fp16 pairs:
// w16[((k2b*NG + row)<<2) | q], k2 = 4*k2b + q covers elements (2*k2, 2*k2+1).
// (n rows also packed; harmlessly unused by rec.)
// ---------------------------------------------------------------------------
__global__ void prep_whh(const float* __restrict__ whh, unsigned int* __restrict__ w16) {
  int idx = blockIdx.x * 256 + threadIdx.x;
  if (idx >= 128 * NG) return;
  int row = idx % NG;
  int k2  = idx / NG;
  half2_t p;
  p[0] = (_Float16)whh[row * NH + 2 * k2];
  p[1] = (_Float16)whh[row * NH + 2 * k2 + 1];
  union { half2_t h; unsigned int u; } cvt;
  cvt.h = p;
  w16[(((k2 >> 2) * NG + row) << 2) | (k2 & 3)] = cvt.u;
}

// ---------------------------------------------------------------------------
// Build the n-gate LDS image: slot(wv, i, lane) at byte wv*8192 + i*1024 +
// lane*16 holds fp16 whh[(512 + j)*256 + s*64 + i*8 + e], e=0..7, where
// j = wv*16 + (lane&15), s = lane>>4.  -> rec's ds_read_b128 per instr i is
// 64 consecutive lanes x 16 B = conflict-free.
// ---------------------------------------------------------------------------
__global__ void prep_n(const float* __restrict__ whh, unsigned int* __restrict__ n_img) {
  int idx32 = blockIdx.x * 256 + threadIdx.x;        // 0..32767
  if (idx32 >= 32768) return;
  int idxh = idx32 * 2;
  int wv   = idxh >> 12;
  int r    = idxh & 4095;
  int i    = r >> 9;
  int r2   = r & 511;
  int lane = r2 >> 3;
  int e    = r2 & 7;                                  // even
  int j    = wv * 16 + (lane & 15);
  int s    = lane >> 4;
  int k    = s * 64 + i * 8 + e;
  half2_t p;
  p[0] = (_Float16)whh[(512 + j) * NH + k];
  p[1] = (_Float16)whh[(512 + j) * NH + k + 1];
  union { half2_t h; unsigned int u; } cvt;
  cvt.h = p;
  n_img[idx32] = cvt.u;
}

// ---------------------------------------------------------------------------
// Fused per-chunk kernel, 1024 threads, 132KB LDS pool (1 WG/CU).
//   blocks [0, rec_count)            : recurrence (1 block = 1 batch element)
//   blocks [rec_count, rec_count+192): gi GEMM for the NEXT chunk
// rec: thread (j = wv*16 + lane&15, s = lane>>4 k-quarter).
//   r,z weights: 16 named u32x4 = 64 VGPRs (peak live ~100 <= 128 cap).
//   n weights  : LDS, conflict-free swizzled image, streamed per step.
// ---------------------------------------------------------------------------
__global__ __launch_bounds__(1024)
void fused_kernel(const int* __restrict__ seq, const float* __restrict__ emb,
                  const float* __restrict__ wih, const float* __restrict__ bih,
                  const float* __restrict__ bhh, const unsigned int* __restrict__ w16,
                  const unsigned int* __restrict__ n_img,
                  const float* __restrict__ rec_gi, float* __restrict__ gi_dst,
                  int gi_t0, float* __restrict__ h_state, float* __restrict__ out,
                  int rec_count, int chunk)
{
  __shared__ __align__(16) char smem[POOL_BYTES];
  const int tid = threadIdx.x;

  if ((int)blockIdx.x < rec_count) {
    // ======================= recurrence =======================
    const int b    = blockIdx.x;
    const int lane = tid & 63;
    const int wv   = tid >> 6;           // 0..15
    const int j    = wv * 16 + (lane & 15);
    const int s    = lane >> 4;          // k-quarter 0..3

    // stage n-gate weights into LDS (own slots; coalesced both sides)
    {
      const char* nsrc = (const char*)n_img;
      const int base = wv * 8192 + lane * 16;
#pragma unroll
      for (int it = 0; it < 8; ++it) {
        *(u32x4*)(smem + base + it * 1024) =
            *(const u32x4*)(nsrc + base + it * 1024);
      }
    }

// ---- r,z weights as 16 named u32x4 scalars (64 VGPRs) ----
#define LOADW(i)                                                              \
  u32x4 wr##i, wz##i;                                                         \
  {                                                                           \
    const unsigned int* base = w16 + (((size_t)(s * 8 + (i)) * NG) << 2);     \
    wr##i = *(const u32x4*)(base + ((size_t)j << 2));                         \
    wz##i = *(const u32x4*)(base + ((size_t)(NH + j) << 2));                  \
  }
    LOADW(0) LOADW(1) LOADW(2) LOADW(3) LOADW(4) LOADW(5) LOADW(6) LOADW(7)
#undef LOADW
    asm volatile("" : "+v"(wr0), "+v"(wr1), "+v"(wr2), "+v"(wr3),
                      "+v"(wr4), "+v"(wr5), "+v"(wr6), "+v"(wr7));
    asm volatile("" : "+v"(wz0), "+v"(wz1), "+v"(wz2), "+v"(wz3),
                      "+v"(wz4), "+v"(wz5), "+v"(wz6), "+v"(wz7));

    const float bn = bhh[2 * NH + j];
    float hreg = 0.f;
    if (chunk != 0) hreg = h_state[b * NH + j];
    if (s == 0) {   // write h element j into buffer 0 (quarter-padded layout)
      *(_Float16*)(smem + H_OFF + ((j >> 6) * H_QSTR) + ((j & 63) * 2)) =
          (_Float16)hreg;
    }
    __syncthreads();

    const float* gpj = rec_gi + (size_t)b * NG + j;
    const char*  nb  = smem + wv * 8192 + lane * 16;

#pragma unroll 1
    for (int t = 0; t < TCH; ++t) {
      const float gr = gpj[0], gz = gpj[NH], gn = gpj[2 * NH];

      float ar = 0.f, az = 0.f, an = 0.f;
      const char* hb = smem + H_OFF + ((t & 1) ? H_BUFSTR : 0) + s * H_QSTR;

#define DOT(i)                                                                \
  {                                                                           \
    U4 hu; hu.q = *(const u32x4*)(hb + ((i) << 4));                           \
    U4 nu; nu.q = *(const u32x4*)(nb + ((i) << 10));                          \
    U4 ru; ru.q = wr##i;                                                      \
    U4 zu; zu.q = wz##i;                                                      \
    ar = dot2f(hu.h[0], ru.h[0], ar);                                         \
    az = dot2f(hu.h[0], zu.h[0], az);                                         \
    an = dot2f(hu.h[0], nu.h[0], an);                                         \
    ar = dot2f(hu.h[1], ru.h[1], ar);                                         \
    az = dot2f(hu.h[1], zu.h[1], az);                                         \
    an = dot2f(hu.h[1], nu.h[1], an);                                         \
    ar = dot2f(hu.h[2], ru.h[2], ar);                                         \
    az = dot2f(hu.h[2], zu.h[2], az);                                         \
    an = dot2f(hu.h[2], nu.h[2], an);                                         \
    ar = dot2f(hu.h[3], ru.h[3], ar);                                         \
    az = dot2f(hu.h[3], zu.h[3], az);                                         \
    an = dot2f(hu.h[3], nu.h[3], an);                                         \
  }
      DOT(0) DOT(1) DOT(2) DOT(3) DOT(4) DOT(5) DOT(6) DOT(7)
#undef DOT

      // butterfly over the 4 k-quarters (lane bits 4 and 5)
      ar += __shfl_xor(ar, 16, 64);  ar += __shfl_xor(ar, 32, 64);
      az += __shfl_xor(az, 16, 64);  az += __shfl_xor(az, 32, 64);
      an += __shfl_xor(an, 16, 64);  an += __shfl_xor(an, 32, 64);

      const float r = sigm(gr + ar);          // b_ih_r + b_hh_r folded into gi
      const float z = sigm(gz + az);          // b_ih_z + b_hh_z folded into gi
      const float n = tanh_fast(gn + r * (an + bn));
      hreg = n + z * (hreg - n);              // (1-z)*n + z*h

      if (s == 0) {
        *(_Float16*)(smem + H_OFF + (((t + 1) & 1) ? H_BUFSTR : 0) +
                     ((j >> 6) * H_QSTR) + ((j & 63) * 2)) = (_Float16)hreg;
      }
      gpj += NB * NG;
      __syncthreads();
    }
    if (s == 0) {
      h_state[b * NH + j] = hreg;
      if (out) out[b * NH + j] = hreg;
    }
  } else {
    // ======================= gi GEMM ==========================
    if (gi_dst == nullptr) return;
    float (*xs)[68]  = (float(*)[68])smem;                 // 17,408 B
    float (*wsh)[68] = (float(*)[68])(smem + 17408);       // 69,632 B
    int*  tok        = (int*)(smem + 17408 + 69632);       //    256 B
    const int gb = blockIdx.x - rec_count;   // 0..191
    const int tl = gb & 63;                  // local timestep
    const int g0 = (gb >> 6) * 256;          // gate-column region
    const int t  = gi_t0 + tl;
    if (tid < 64) tok[tid] = seq[tid * TSEQ + t];
    const int tx = tid & 31;                 // 32 col groups
    const int ty = tid >> 5;                 // 32 row groups of 2
    float acc[2][8];
#pragma unroll
    for (int i = 0; i < 2; ++i)
#pragma unroll
      for (int c8 = 0; c8 < 8; ++c8) acc[i][c8] = 0.f;

    for (int kb = 0; kb < 4; ++kb) {
      __syncthreads();                       // covers tok on first iter
      {
        int r = tid >> 4, c = tid & 15;      // 1024 float4 = whole 64x64 x-tile
        *(float4*)(&xs[r][c * 4]) =
            *(const float4*)(emb + (size_t)tok[r] * NE + kb * 64 + c * 4);
      }
#pragma unroll
      for (int it = 0; it < 4; ++it) {
        int i = it * 1024 + tid;
        int r = i >> 4, c = i & 15;
        *(float4*)(&wsh[r][c * 4]) =
            *(const float4*)(wih + (size_t)(g0 + r) * NE + kb * 64 + c * 4);
      }
      __syncthreads();
#pragma unroll 4
      for (int k4 = 0; k4 < 16; ++k4) {
        float4 xf[2], wf[8];
#pragma unroll
        for (int i = 0; i < 2; ++i) xf[i] = *(const float4*)(&xs[ty * 2 + i][k4 * 4]);
#pragma unroll
        for (int c8 = 0; c8 < 8; ++c8) wf[c8] = *(const float4*)(&wsh[tx + 32 * c8][k4 * 4]);
#pragma unroll
        for (int i = 0; i < 2; ++i)
#pragma unroll
          for (int c8 = 0; c8 < 8; ++c8)
            acc[i][c8] += xf[i].x * wf[c8].x + xf[i].y * wf[c8].y +
                          xf[i].z * wf[c8].z + xf[i].w * wf[c8].w;
      }
    }
#pragma unroll
    for (int i = 0; i < 2; ++i) {
      const int brow = ty * 2 + i;
      float* dst = gi_dst + ((size_t)(tl * NB + brow)) * NG + g0;
#pragma unroll
      for (int c8 = 0; c8 < 8; ++c8) {
        const int col = tx + 32 * c8;
        const int g = g0 + col;
        float bias = bih[g] + (g < 2 * NH ? bhh[g] : 0.f);
        dst[col] = acc[i][c8] + bias;
      }
    }
  }
}

extern "C" void kernel_launch(void* const* d_in, const int* in_sizes, int n_in,
                              void* d_out, int out_size, void* d_ws, size_t ws_size,
                              hipStream_t stream) {
  (void)in_sizes; (void)n_in; (void)out_size; (void)ws_size;
  const int*   seq = (const int*)d_in[0];
  const float* emb = (const float*)d_in[1];
  const float* wih = (const float*)d_in[2];
  const float* whh = (const float*)d_in[3];
  const float* bih = (const float*)d_in[4];
  const float* bhh = (const float*)d_in[5];
  float* out = (float*)d_out;
  char*  ws  = (char*)d_ws;

  unsigned int* w16     = (unsigned int*)(ws);             //   393,216 B
  unsigned int* n_img   = (unsigned int*)(ws + 393216);    //   131,072 B
  float*        h_state = (float*)(ws + 524288);           //    65,536 B
  float*        gi0     = (float*)(ws + 589824);           // 12,582,912 B
  float*        gi1     = (float*)(ws + 589824 + 12582912);

  prep_whh<<<dim3(384), dim3(256), 0, stream>>>(whh, w16);
  prep_n  <<<dim3(128), dim3(256), 0, stream>>>(whh, n_img);

  // prologue: gi for chunk 0 only
  fused_kernel<<<dim3(192), dim3(1024), 0, stream>>>(
      seq, emb, wih, bih, bhh, w16, n_img,
      nullptr, gi0, 0, h_state, nullptr, 0, 0);

  for (int c = 0; c < NCHUNK; ++c) {
    float* rd  = (c & 1) ? gi1 : gi0;
    float* wr_ = (c & 1) ? gi0 : gi1;
    const bool last = (c == NCHUNK - 1);
    const int grid  = last ? NB : NB + 192;
    fused_kernel<<<dim3(grid), dim3(1024), 0, stream>>>(
        seq, emb, wih, bih, bhh, w16, n_img,
        rd, last ? nullptr : wr_, (c + 1) * TCH, h_state,
        last ? out : nullptr, NB, c);
  }
}

// Round 7
// 2599.251 us; speedup vs baseline: 1.0655x; 1.0655x over previous
//
#include <hip/hip_runtime.h>
#include <hip/hip_fp16.h>

#define TSEQ   2048
#define NB     64
#define NE     256
#define NH     256
#define NG     768
#define TCH    64
#define NCHUNK (TSEQ / TCH)
#define POOL_BYTES 87552

// ---------------------------------------------------------------------------
// Pack w_hh into the per-thread-contiguous fp16 layout consumed by the asm
// loop: thread (j, s) owns 768 B at byte offset (j*2+s)*768:
//   [g in {r,z,n}][i in 0..15] quad (16 B) ; quad u32 c = fp16 pair of
//   whh[(g*256 + j)][ s*128 + i*8 + 2c , +1 ].
// ---------------------------------------------------------------------------
__global__ void prep_whh(const float* __restrict__ whh, unsigned int* __restrict__ w16) {
  int idx = blockIdx.x * 256 + threadIdx.x;        // u32 index, 0..98303
  if (idx >= 98304) return;
  int c  = idx & 3;
  int i  = (idx >> 2) & 15;
  int g  = (idx >> 6) % 3;
  int js = idx / 192;
  int s  = js & 1;
  int j  = js >> 1;
  int k  = s * 128 + i * 8 + 2 * c;
  const float* src = whh + (size_t)(g * 256 + j) * 256 + k;
  union { struct { _Float16 a, b; } h; unsigned int u; } cvt;
  cvt.h.a = (_Float16)src[0];
  cvt.h.b = (_Float16)src[1];
  w16[idx] = cvt.u;
}

// ---- asm building blocks ---------------------------------------------------
#define DOT12(H0,H1,H2,H3,R0,R1,R2,R3,Z0,Z1,Z2,Z3,N0,N1,N2,N3) \
  "v_dot2_f32_f16 v16, v" H0 ", v" R0 ", v16\n\t" \
  "v_dot2_f32_f16 v17, v" H0 ", v" Z0 ", v17\n\t" \
  "v_dot2_f32_f16 v18, v" H0 ", v" N0 ", v18\n\t" \
  "v_dot2_f32_f16 v16, v" H1 ", v" R1 ", v16\n\t" \
  "v_dot2_f32_f16 v17, v" H1 ", v" Z1 ", v17\n\t" \
  "v_dot2_f32_f16 v18, v" H1 ", v" N1 ", v18\n\t" \
  "v_dot2_f32_f16 v16, v" H2 ", v" R2 ", v16\n\t" \
  "v_dot2_f32_f16 v17, v" H2 ", v" Z2 ", v17\n\t" \
  "v_dot2_f32_f16 v18, v" H2 ", v" N2 ", v18\n\t" \
  "v_dot2_f32_f16 v16, v" H3 ", v" R3 ", v16\n\t" \
  "v_dot2_f32_f16 v17, v" H3 ", v" Z3 ", v17\n\t" \
  "v_dot2_f32_f16 v18, v" H3 ", v" N3 ", v18\n\t"

#define RSTEP(O0,O1,O2,O3,O4,O5,O6,O7,O8,O9,O10,O11,O12,O13,O14,O15) \
  "global_load_dword v12, v3, %[gip]\n\t" \
  "global_load_dword v13, v3, %[gip] offset:1024\n\t" \
  "global_load_dword v14, v3, %[gip] offset:2048\n\t" \
  "v_add_u32 v3, 0x30000, v3\n\t" \
  "v_mov_b32 v16, 0\n\t" \
  "v_mov_b32 v17, 0\n\t" \
  "v_mov_b32 v18, 0\n\t" \
  "ds_read_b128 v[4:7], v2 offset:" O0 "\n\t" \
  "ds_read_b128 v[8:11], v2 offset:" O1 "\n\t" \
  "s_waitcnt lgkmcnt(1)\n\t" \
  DOT12("4","5","6","7",  "64","65","66","67",    "128","129","130","131","192","193","194","195") \
  "ds_read_b128 v[4:7], v2 offset:" O2 "\n\t" \
  "s_waitcnt lgkmcnt(1)\n\t" \
  DOT12("8","9","10","11","68","69","70","71",    "132","133","134","135","196","197","198","199") \
  "ds_read_b128 v[8:11], v2 offset:" O3 "\n\t" \
  "s_waitcnt lgkmcnt(1)\n\t" \
  DOT12("4","5","6","7",  "72","73","74","75",    "136","137","138","139","200","201","202","203") \
  "ds_read_b128 v[4:7], v2 offset:" O4 "\n\t" \
  "s_waitcnt lgkmcnt(1)\n\t" \
  DOT12("8","9","10","11","76","77","78","79",    "140","141","142","143","204","205","206","207") \
  "ds_read_b128 v[8:11], v2 offset:" O5 "\n\t" \
  "s_waitcnt lgkmcnt(1)\n\t" \
  DOT12("4","5","6","7",  "80","81","82","83",    "144","145","146","147","208","209","210","211") \
  "ds_read_b128 v[4:7], v2 offset:" O6 "\n\t" \
  "s_waitcnt lgkmcnt(1)\n\t" \
  DOT12("8","9","10","11","84","85","86","87",    "148","149","150","151","212","213","214","215") \
  "ds_read_b128 v[8:11], v2 offset:" O7 "\n\t" \
  "s_waitcnt lgkmcnt(1)\n\t" \
  DOT12("4","5","6","7",  "88","89","90","91",    "152","153","154","155","216","217","218","219") \
  "ds_read_b128 v[4:7], v2 offset:" O8 "\n\t" \
  "s_waitcnt lgkmcnt(1)\n\t" \
  DOT12("8","9","10","11","92","93","94","95",    "156","157","158","159","220","221","222","223") \
  "ds_read_b128 v[8:11], v2 offset:" O9 "\n\t" \
  "s_waitcnt lgkmcnt(1)\n\t" \
  DOT12("4","5","6","7",  "96","97","98","99",    "160","161","162","163","224","225","226","227") \
  "ds_read_b128 v[4:7], v2 offset:" O10 "\n\t" \
  "s_waitcnt lgkmcnt(1)\n\t" \
  DOT12("8","9","10","11","100","101","102","103","164","165","166","167","228","229","230","231") \
  "ds_read_b128 v[8:11], v2 offset:" O11 "\n\t" \
  "s_waitcnt lgkmcnt(1)\n\t" \
  DOT12("4","5","6","7",  "104","105","106","107","168","169","170","171","232","233","234","235") \
  "ds_read_b128 v[4:7], v2 offset:" O12 "\n\t" \
  "s_waitcnt lgkmcnt(1)\n\t" \
  DOT12("8","9","10","11","108","109","110","111","172","173","174","175","236","237","238","239") \
  "ds_read_b128 v[8:11], v2 offset:" O13 "\n\t" \
  "s_waitcnt lgkmcnt(1)\n\t" \
  DOT12("4","5","6","7",  "112","113","114","115","176","177","178","179","240","241","242","243") \
  "ds_read_b128 v[4:7], v2 offset:" O14 "\n\t" \
  "s_waitcnt lgkmcnt(1)\n\t" \
  DOT12("8","9","10","11","116","117","118","119","180","181","182","183","244","245","246","247") \
  "ds_read_b128 v[8:11], v2 offset:" O15 "\n\t" \
  "s_waitcnt lgkmcnt(1)\n\t" \
  DOT12("4","5","6","7",  "120","121","122","123","184","185","186","187","248","249","250","251") \
  "s_waitcnt lgkmcnt(0)\n\t" \
  DOT12("8","9","10","11","124","125","126","127","188","189","190","191","252","253","254","255")

#define REC_TAIL(WOF) \
  "ds_bpermute_b32 v20, v19, v16\n\t" \
  "ds_bpermute_b32 v21, v19, v17\n\t" \
  "ds_bpermute_b32 v22, v19, v18\n\t" \
  "s_waitcnt lgkmcnt(0)\n\t" \
  "v_add_f32 v16, v16, v20\n\t" \
  "v_add_f32 v17, v17, v21\n\t" \
  "v_add_f32 v18, v18, v22\n\t" \
  "s_waitcnt vmcnt(0)\n\t" \
  "v_add_f32 v20, v12, v16\n\t" \
  "v_mul_f32 v20, 0xbfb8aa3b, v20\n\t" \
  "v_exp_f32 v20, v20\n\t" \
  "s_nop 0\n\t" \
  "v_add_f32 v20, 1.0, v20\n\t" \
  "v_rcp_f32 v20, v20\n\t" \
  "s_nop 0\n\t" \
  "v_add_f32 v21, v13, v17\n\t" \
  "v_mul_f32 v21, 0xbfb8aa3b, v21\n\t" \
  "v_exp_f32 v21, v21\n\t" \
  "s_nop 0\n\t" \
  "v_add_f32 v21, 1.0, v21\n\t" \
  "v_rcp_f32 v21, v21\n\t" \
  "s_nop 0\n\t" \
  "v_add_f32 v22, v18, v28\n\t" \
  "v_fma_f32 v22, v20, v22, v14\n\t" \
  "v_min_f32 v22, 0x41700000, v22\n\t" \
  "v_mul_f32 v22, 0x4038aa3b, v22\n\t" \
  "v_exp_f32 v22, v22\n\t" \
  "s_nop 0\n\t" \
  "v_add_f32 v23, -1.0, v22\n\t" \
  "v_add_f32 v22, 1.0, v22\n\t" \
  "v_rcp_f32 v22, v22\n\t" \
  "s_nop 0\n\t" \
  "v_mul_f32 v22, v23, v22\n\t" \
  "v_sub_f32 v23, v24, v22\n\t" \
  "v_fma_f32 v24, v21, v23, v22\n\t" \
  "v_cvt_f16_f32 v25, v24\n\t" \
  "ds_write_b16 v29, v25 offset:" WOF "\n\t" \
  "s_waitcnt lgkmcnt(0)\n\t" \
  "s_barrier\n\t"

#define WLD(D0,D1,OFF) \
  "global_load_dwordx4 v[" D0 ":" D1 "], %[wof], %[wptr] offset:" OFF "\n\t"

// ---------------------------------------------------------------------------
// Fused per-chunk kernel, 512 threads.
//   blocks [0, rec_count)            : recurrence (1 block = 1 batch element)
//   blocks [rec_count, rec_count+192): gi GEMM for the NEXT chunk
// rec inner loop is hand-written asm; weights pinned in v[64:255].
// ---------------------------------------------------------------------------
__global__ __launch_bounds__(512)
void fused_kernel(const int* __restrict__ seq, const float* __restrict__ emb,
                  const float* __restrict__ wih, const float* __restrict__ bih,
                  const float* __restrict__ bhh, const unsigned int* __restrict__ w16,
                  const float* __restrict__ rec_gi, float* __restrict__ gi_dst,
                  int gi_t0, float* __restrict__ h_state, float* __restrict__ out,
                  int rec_count, int chunk)
{
  __shared__ __align__(16) char smem[POOL_BYTES];
  const int tid = threadIdx.x;

  if ((int)blockIdx.x < rec_count) {
    // ======================= recurrence (asm) =======================
    const int b = blockIdx.x;
    const unsigned lane = tid & 63;
    const unsigned jj   = (unsigned)(tid >> 6) * 32 + (lane & 31);
    const unsigned sh   = lane >> 5;

    float h0 = 0.f;
    if (chunk != 0) h0 = h_state[b * NH + jj];
    const float bnv = bhh[2 * NH + jj];
    ((_Float16*)smem)[jj] = (_Float16)h0;   // h buffer 0 (dup same-value writes OK)
    __syncthreads();

    const unsigned pool0 = (unsigned)(uintptr_t)(smem);
    const unsigned hrd = pool0 + sh * 256;         // h read base (+ s-half)
    const unsigned hwa = pool0 + jj * 2;           // h write addr (b16)
    const unsigned gio = jj * 4;                   // gi byte offset
    const unsigned bpa = (lane ^ 32u) << 2;        // bpermute partner addr
    const unsigned wof = (jj * 2 + sh) * 768;      // weight block byte offset
    const float* gib = rec_gi + (size_t)b * NG;

    float hout;
    asm volatile(
      "v_mov_b32 v2, %[hrd]\n\t"
      "v_mov_b32 v3, %[gio]\n\t"
      "v_mov_b32 v19, %[bpa]\n\t"
      "v_mov_b32 v24, %[h0]\n\t"
      "v_mov_b32 v28, %[bn]\n\t"
      "v_mov_b32 v29, %[hwa]\n\t"
      WLD("64","67","0")    WLD("68","71","16")   WLD("72","75","32")   WLD("76","79","48")
      WLD("80","83","64")   WLD("84","87","80")   WLD("88","91","96")   WLD("92","95","112")
      WLD("96","99","128")  WLD("100","103","144")WLD("104","107","160")WLD("108","111","176")
      WLD("112","115","192")WLD("116","119","208")WLD("120","123","224")WLD("124","127","240")
      WLD("128","131","256")WLD("132","135","272")WLD("136","139","288")WLD("140","143","304")
      WLD("144","147","320")WLD("148","151","336")WLD("152","155","352")WLD("156","159","368")
      WLD("160","163","384")WLD("164","167","400")WLD("168","171","416")WLD("172","175","432")
      WLD("176","179","448")WLD("180","183","464")WLD("184","187","480")WLD("188","191","496")
      WLD("192","195","512")WLD("196","199","528")WLD("200","203","544")WLD("204","207","560")
      WLD("208","211","576")WLD("212","215","592")WLD("216","219","608")WLD("220","223","624")
      WLD("224","227","640")WLD("228","231","656")WLD("232","235","672")WLD("236","239","688")
      WLD("240","243","704")WLD("244","247","720")WLD("248","251","736")WLD("252","255","752")
      "s_waitcnt vmcnt(0)\n\t"
      "s_mov_b32 s20, 32\n\t"
      "1:\n\t"
      RSTEP("0","16","32","48","64","80","96","112",
            "128","144","160","176","192","208","224","240")
      REC_TAIL("512")
      RSTEP("512","528","544","560","576","592","608","624",
            "640","656","672","688","704","720","736","752")
      REC_TAIL("0")
      "s_sub_u32 s20, s20, 1\n\t"
      "s_cmp_lg_u32 s20, 0\n\t"
      "s_cbranch_scc1 1b\n\t"
      "v_mov_b32 %[hout], v24\n\t"
      : [hout] "=v"(hout)
      : [hrd] "v"(hrd), [gio] "v"(gio), [bpa] "v"(bpa), [h0] "v"(h0),
        [bn] "v"(bnv), [hwa] "v"(hwa), [wof] "v"(wof),
        [wptr] "s"(w16), [gip] "s"(gib)
      : "memory","scc","s20",
        "v2","v3","v4","v5","v6","v7","v8","v9","v10","v11","v12","v13","v14",
        "v16","v17","v18","v19","v20","v21","v22","v23","v24","v25","v28","v29",
        "v64","v65","v66","v67","v68","v69","v70","v71","v72","v73","v74","v75",
        "v76","v77","v78","v79","v80","v81","v82","v83","v84","v85","v86","v87",
        "v88","v89","v90","v91","v92","v93","v94","v95","v96","v97","v98","v99",
        "v100","v101","v102","v103","v104","v105","v106","v107","v108","v109",
        "v110","v111","v112","v113","v114","v115","v116","v117","v118","v119",
        "v120","v121","v122","v123","v124","v125","v126","v127","v128","v129",
        "v130","v131","v132","v133","v134","v135","v136","v137","v138","v139",
        "v140","v141","v142","v143","v144","v145","v146","v147","v148","v149",
        "v150","v151","v152","v153","v154","v155","v156","v157","v158","v159",
        "v160","v161","v162","v163","v164","v165","v166","v167","v168","v169",
        "v170","v171","v172","v173","v174","v175","v176","v177","v178","v179",
        "v180","v181","v182","v183","v184","v185","v186","v187","v188","v189",
        "v190","v191","v192","v193","v194","v195","v196","v197","v198","v199",
        "v200","v201","v202","v203","v204","v205","v206","v207","v208","v209",
        "v210","v211","v212","v213","v214","v215","v216","v217","v218","v219",
        "v220","v221","v222","v223","v224","v225","v226","v227","v228","v229",
        "v230","v231","v232","v233","v234","v235","v236","v237","v238","v239",
        "v240","v241","v242","v243","v244","v245","v246","v247","v248","v249",
        "v250","v251","v252","v253","v254","v255");

    h_state[b * NH + jj] = hout;
    if (out) out[b * NH + jj] = hout;
  } else {
    // ======================= gi GEMM ==========================
    if (gi_dst == nullptr) return;
    float (*xs)[68]  = (float(*)[68])smem;                 // 17,408 B
    float (*wsh)[68] = (float(*)[68])(smem + 17408);       // 69,632 B
    int*  tok        = (int*)(smem + 17408 + 69632);       //    256 B
    const int gb = blockIdx.x - rec_count;   // 0..191
    const int tl = gb & 63;                  // local timestep
    const int g0 = (gb >> 6) * 256;          // gate-column region
    const int t  = gi_t0 + tl;
    if (tid < 64) tok[tid] = seq[tid * TSEQ + t];
    const int tx = tid & 31;                 // 32 col groups
    const int ty = tid >> 5;                 // 16 row groups of 4
    float acc[4][8];
#pragma unroll
    for (int i = 0; i < 4; ++i)
#pragma unroll
      for (int c8 = 0; c8 < 8; ++c8) acc[i][c8] = 0.f;

    for (int kb = 0; kb < 4; ++kb) {
      __syncthreads();                       // covers tok on first iter
#pragma unroll
      for (int it = 0; it < 2; ++it) {
        int i = it * 512 + tid;
        int r = i >> 4, c = i & 15;
        *(float4*)(&xs[r][c * 4]) =
            *(const float4*)(emb + (size_t)tok[r] * NE + kb * 64 + c * 4);
      }
#pragma unroll
      for (int it = 0; it < 8; ++it) {
        int i = it * 512 + tid;
        int r = i >> 4, c = i & 15;
        *(float4*)(&wsh[r][c * 4]) =
            *(const float4*)(wih + (size_t)(g0 + r) * NE + kb * 64 + c * 4);
      }
      __syncthreads();
#pragma unroll 4
      for (int k4 = 0; k4 < 16; ++k4) {
        float4 xf[4], wf[8];
#pragma unroll
        for (int i = 0; i < 4; ++i) xf[i] = *(const float4*)(&xs[ty * 4 + i][k4 * 4]);
#pragma unroll
        for (int c8 = 0; c8 < 8; ++c8) wf[c8] = *(const float4*)(&wsh[tx + 32 * c8][k4 * 4]);
#pragma unroll
        for (int i = 0; i < 4; ++i)
#pragma unroll
          for (int c8 = 0; c8 < 8; ++c8)
            acc[i][c8] += xf[i].x * wf[c8].x + xf[i].y * wf[c8].y +
                          xf[i].z * wf[c8].z + xf[i].w * wf[c8].w;
      }
    }
#pragma unroll
    for (int i = 0; i < 4; ++i) {
      const int brow = ty * 4 + i;
      float* dst = gi_dst + ((size_t)(tl * NB + brow)) * NG + g0;
#pragma unroll
      for (int c8 = 0; c8 < 8; ++c8) {
        const int col = tx + 32 * c8;
        const int g = g0 + col;
        float bias = bih[g] + (g < 2 * NH ? bhh[g] : 0.f);
        dst[col] = acc[i][c8] + bias;
      }
    }
  }
}

extern "C" void kernel_launch(void* const* d_in, const int* in_sizes, int n_in,
                              void* d_out, int out_size, void* d_ws, size_t ws_size,
                              hipStream_t stream) {
  (void)in_sizes; (void)n_in; (void)out_size; (void)ws_size;
  const int*   seq = (const int*)d_in[0];
  const float* emb = (const float*)d_in[1];
  const float* wih = (const float*)d_in[2];
  const float* whh = (const float*)d_in[3];
  const float* bih = (const float*)d_in[4];
  const float* bhh = (const float*)d_in[5];
  float* out = (float*)d_out;
  char*  ws  = (char*)d_ws;

  unsigned int* w16     = (unsigned int*)(ws);            // 393,216 B
  float*        h_state = (float*)(ws + 393216);          //  65,536 B
  float*        gi0     = (float*)(ws + 458752);          // 12,582,912 B
  float*        gi1     = (float*)(ws + 458752 + 12582912);

  prep_whh<<<dim3(384), dim3(256), 0, stream>>>(whh, w16);

  // prologue: gi for chunk 0 only
  fused_kernel<<<dim3(192), dim3(512), 0, stream>>>(
      seq, emb, wih, bih, bhh, w16,
      nullptr, gi0, 0, h_state, nullptr, 0, 0);

  for (int c = 0; c < NCHUNK; ++c) {
    float* rd  = (c & 1) ? gi1 : gi0;
    float* wr_ = (c & 1) ? gi0 : gi1;
    const bool last = (c == NCHUNK - 1);
    const int grid  = last ? NB : NB + 192;
    fused_kernel<<<dim3(grid), dim3(512), 0, stream>>>(
        seq, emb, wih, bih, bhh, w16,
        rd, last ? nullptr : wr_, (c + 1) * TCH, h_state,
        last ? out : nullptr, NB, c);
  }
}